// Round 1
// baseline (480.936 us; speedup 1.0000x reference)
//
#include <hip/hip_runtime.h>
#include <math.h>

#define C_ 32
#define D_ 48
#define H_ 128
#define W_ 160
#define HW_ (H_*W_)
#define DHW_ (D_*HW_)

// ---------------- small matrix helpers (device, used by 1-thread setup) ----

__device__ __forceinline__ void combine4(const float* p, float* out) {
    // p: 32 floats. p[0..15] = extrinsic E, p[16..31] = K.
    // out = E with top 3x4 replaced by K[:3,:3] @ E[:3,:4]
    #pragma unroll
    for (int i = 0; i < 16; ++i) out[i] = p[i];
    #pragma unroll
    for (int i = 0; i < 3; ++i) {
        #pragma unroll
        for (int j = 0; j < 4; ++j) {
            float s = 0.f;
            #pragma unroll
            for (int k = 0; k < 3; ++k) s += p[16 + i*4 + k] * p[k*4 + j];
            out[i*4 + j] = s;
        }
    }
}

__device__ void inv4(const float* A, float* out) {
    // Gauss-Jordan with partial pivoting
    float M[4][8];
    for (int i = 0; i < 4; ++i)
        for (int j = 0; j < 4; ++j) {
            M[i][j] = A[i*4 + j];
            M[i][4 + j] = (i == j) ? 1.f : 0.f;
        }
    for (int c = 0; c < 4; ++c) {
        int piv = c; float best = fabsf(M[c][c]);
        for (int r = c + 1; r < 4; ++r) {
            float a = fabsf(M[r][c]);
            if (a > best) { best = a; piv = r; }
        }
        if (piv != c)
            for (int j = 0; j < 8; ++j) { float t = M[c][j]; M[c][j] = M[piv][j]; M[piv][j] = t; }
        float ip = 1.f / M[c][c];
        for (int j = 0; j < 8; ++j) M[c][j] *= ip;
        for (int r = 0; r < 4; ++r) if (r != c) {
            float f = M[r][c];
            for (int j = 0; j < 8; ++j) M[r][j] -= f * M[c][j];
        }
    }
    for (int i = 0; i < 4; ++i)
        for (int j = 0; j < 4; ++j) out[i*4 + j] = M[i][4 + j];
}

__device__ __forceinline__ void matmul4(const float* A, const float* B, float* Cm) {
    #pragma unroll
    for (int i = 0; i < 4; ++i)
        #pragma unroll
        for (int j = 0; j < 4; ++j) {
            float s = 0.f;
            #pragma unroll
            for (int k = 0; k < 4; ++k) s += A[i*4 + k] * B[k*4 + j];
            Cm[i*4 + j] = s;
        }
}

// proj_out: per view v: [v*12 + 0..8] = rot row-major, [v*12 + 9..11] = trans
__global__ void proj_setup_kernel(const float* __restrict__ refp,
                                  const float* __restrict__ sp1,
                                  const float* __restrict__ sp2,
                                  float* __restrict__ proj_out) {
    if (threadIdx.x != 0 || blockIdx.x != 0) return;
    float rc[16], s1[16], s2[16], ri[16], p[16];
    combine4(refp, rc);
    combine4(sp1, s1);
    combine4(sp2, s2);
    inv4(rc, ri);
    for (int v = 0; v < 2; ++v) {
        matmul4(v == 0 ? s1 : s2, ri, p);
        for (int i = 0; i < 3; ++i)
            for (int j = 0; j < 3; ++j) proj_out[v*12 + i*3 + j] = p[i*4 + j];
        for (int i = 0; i < 3; ++i) proj_out[v*12 + 9 + i] = p[i*4 + 3];
    }
}

// ---------------- warp + variance -----------------------------------------
// One thread per (d,y,x). Warp math done once, channel loop does the gathers.
// Output layout: var[c][d][y][x]  (C,D,H,W)

__global__ __launch_bounds__(256) void variance_kernel(
        const float* __restrict__ ref,
        const float* __restrict__ s1g,
        const float* __restrict__ s2g,
        const float* __restrict__ depthv,
        const float* __restrict__ proj,
        float* __restrict__ var) {
    int idx = blockIdx.x * 256 + threadIdx.x;   // < DHW_
    int x = idx % W_;
    int t = idx / W_;
    int y = t % H_;
    float depth = depthv[idx];
    float fx = (float)x, fy = (float)y;

    int off[2][4];
    float wt[2][4];
    #pragma unroll
    for (int v = 0; v < 2; ++v) {
        const float* P = proj + v*12;
        float rx = P[0]*fx + P[1]*fy + P[2];
        float ry = P[3]*fx + P[4]*fy + P[5];
        float rz = P[6]*fx + P[7]*fy + P[8];
        float X = rx*depth + P[9];
        float Y = ry*depth + P[10];
        float Z = rz*depth + P[11];
        float z = (fabsf(Z) < 1e-6f) ? 1e-6f : Z;
        float px = X / z;
        float py = Y / z;
        float x0f = floorf(px), y0f = floorf(py);
        float wx = px - x0f, wy = py - y0f;
        #pragma unroll
        for (int k = 0; k < 4; ++k) {
            float xi = x0f + (float)(k & 1);
            float yi = y0f + (float)(k >> 1);
            bool valid = (xi >= 0.f) && (xi <= (float)(W_-1)) &&
                         (yi >= 0.f) && (yi <= (float)(H_-1));
            int xc = (int)fminf(fmaxf(xi, 0.f), (float)(W_-1));
            int yc = (int)fminf(fmaxf(yi, 0.f), (float)(H_-1));
            off[v][k] = yc * W_ + xc;
            float w = ((k & 1) ? wx : 1.f - wx) * ((k >> 1) ? wy : 1.f - wy);
            wt[v][k] = valid ? w : 0.f;
        }
    }

    int pix = y*W_ + x;
    size_t obase = (size_t)idx;                 // d*HW_ + pix == idx
    const float inv3 = 1.f / 3.f;
    #pragma unroll 4
    for (int c = 0; c < C_; ++c) {
        const float* p1 = s1g + c*HW_;
        const float* p2 = s2g + c*HW_;
        float r = ref[c*HW_ + pix];
        float wv1 = wt[0][0]*p1[off[0][0]] + wt[0][1]*p1[off[0][1]]
                  + wt[0][2]*p1[off[0][2]] + wt[0][3]*p1[off[0][3]];
        float wv2 = wt[1][0]*p2[off[1][0]] + wt[1][1]*p2[off[1][1]]
                  + wt[1][2]*p2[off[1][2]] + wt[1][3]*p2[off[1][3]];
        float s = r + wv1 + wv2;
        float q = r*r + wv1*wv1 + wv2*wv2;
        float m = s * inv3;
        var[(size_t)c*DHW_ + obase] = q*inv3 - m*m;
    }
}

// ---------------- 3D conv, SAME padding, NCDHW ----------------------------
// Block = 32x8 (x,y) plane, TD=4 depth outputs per thread.
// Per-ic LDS tile (TD+2)x(TH+2)x(TW+2); weights read uniformly (s_load path).

template<int IC, int OC, bool RELU>
__global__ __launch_bounds__(256) void conv3d_kernel(
        const float* __restrict__ in,
        const float* __restrict__ wgt,   // (OC, IC, 3,3,3)
        const float* __restrict__ bias,  // (OC)
        float* __restrict__ out) {
    const int TW = 32, TH = 8, TD = 4;
    const int tx = threadIdx.x & 31;
    const int ty = threadIdx.x >> 5;
    const int x0 = blockIdx.x * TW;
    const int y0 = blockIdx.y * TH;
    const int d0 = blockIdx.z * TD;

    __shared__ float tile[(TD+2)*(TH+2)*(TW+2)];   // 6*10*34 = 2040 floats

    float acc[TD][OC];
    #pragma unroll
    for (int od = 0; od < TD; ++od)
        #pragma unroll
        for (int oc = 0; oc < OC; ++oc) acc[od][oc] = bias[oc];

    for (int ic = 0; ic < IC; ++ic) {
        __syncthreads();
        const float* inc = in + (size_t)ic * DHW_;
        for (int li = threadIdx.x; li < (TD+2)*(TH+2)*(TW+2); li += 256) {
            int lx = li % (TW+2);
            int lt = li / (TW+2);
            int ly = lt % (TH+2);
            int ld = lt / (TH+2);
            int gx = x0 + lx - 1;
            int gy = y0 + ly - 1;
            int gd = d0 + ld - 1;
            float v = 0.f;
            if (gx >= 0 && gx < W_ && gy >= 0 && gy < H_ && gd >= 0 && gd < D_)
                v = inc[gd*HW_ + gy*W_ + gx];
            tile[li] = v;
        }
        __syncthreads();

        // register-cache the 6x3x3 neighborhood for this thread
        float vreg[TD+2][3][3];
        #pragma unroll
        for (int p = 0; p < TD+2; ++p)
            #pragma unroll
            for (int i = 0; i < 3; ++i)
                #pragma unroll
                for (int j = 0; j < 3; ++j)
                    vreg[p][i][j] = tile[(p*(TH+2) + ty + i)*(TW+2) + tx + j];

        #pragma unroll
        for (int od = 0; od < TD; ++od)
            #pragma unroll
            for (int kd = 0; kd < 3; ++kd)
                #pragma unroll
                for (int i = 0; i < 3; ++i)
                    #pragma unroll
                    for (int j = 0; j < 3; ++j) {
                        float val = vreg[od + kd][i][j];
                        #pragma unroll
                        for (int oc = 0; oc < OC; ++oc)
                            acc[od][oc] = fmaf(
                                wgt[((oc*IC + ic)*27) + kd*9 + i*3 + j],
                                val, acc[od][oc]);
                    }
    }

    #pragma unroll
    for (int od = 0; od < TD; ++od) {
        int obase = (d0 + od)*HW_ + (y0 + ty)*W_ + (x0 + tx);
        #pragma unroll
        for (int oc = 0; oc < OC; ++oc) {
            float r = acc[od][oc];
            if (RELU) r = fmaxf(r, 0.f);
            out[(size_t)oc*DHW_ + obase] = r;
        }
    }
}

// ---------------- softmax over D ------------------------------------------

__global__ __launch_bounds__(256) void softmax_kernel(
        const float* __restrict__ logits, float* __restrict__ out) {
    int pix = blockIdx.x * 256 + threadIdx.x;   // < HW_
    float v[D_];
    float m = -1e30f;
    #pragma unroll
    for (int d = 0; d < D_; ++d) {
        v[d] = logits[d*HW_ + pix];
        m = fmaxf(m, v[d]);
    }
    float s = 0.f;
    #pragma unroll
    for (int d = 0; d < D_; ++d) {
        v[d] = expf(v[d] - m);
        s += v[d];
    }
    float is = 1.f / s;
    #pragma unroll
    for (int d = 0; d < D_; ++d) out[d*HW_ + pix] = v[d] * is;
}

// ---------------- launch ---------------------------------------------------

extern "C" void kernel_launch(void* const* d_in, const int* in_sizes, int n_in,
                              void* d_out, int out_size, void* d_ws, size_t ws_size,
                              hipStream_t stream) {
    const float* ref_fea = (const float*)d_in[0];
    const float* src1    = (const float*)d_in[1];
    const float* src2    = (const float*)d_in[2];
    const float* ref_prj = (const float*)d_in[3];
    const float* src_pr1 = (const float*)d_in[4];
    const float* src_pr2 = (const float*)d_in[5];
    const float* depth   = (const float*)d_in[6];
    const float* w1      = (const float*)d_in[7];
    const float* b1      = (const float*)d_in[8];
    const float* w2      = (const float*)d_in[9];
    const float* b2      = (const float*)d_in[10];
    float* out = (float*)d_out;

    char* ws = (char*)d_ws;
    float* proj   = (float*)ws;                                        // 24 floats
    float* var    = (float*)(ws + 256);                                // 32*DHW f32 (126 MB)
    float* hid    = (float*)(ws + 256 + (size_t)C_*DHW_*sizeof(float)); // 8*DHW f32 (31.5 MB)
    float* logits = var;  // variance region is dead after conv1 -> reuse

    proj_setup_kernel<<<1, 64, 0, stream>>>(ref_prj, src_pr1, src_pr2, proj);

    variance_kernel<<<DHW_/256, 256, 0, stream>>>(ref_fea, src1, src2, depth, proj, var);

    dim3 cgrid(W_/32, H_/8, D_/4);   // 5 x 16 x 12
    conv3d_kernel<32, 8, true ><<<cgrid, 256, 0, stream>>>(var, w1, b1, hid);
    conv3d_kernel< 8, 1, false><<<cgrid, 256, 0, stream>>>(hid, w2, b2, logits);

    softmax_kernel<<<HW_/256, 256, 0, stream>>>(logits, out);
}